// Round 3
// baseline (232.391 us; speedup 1.0000x reference)
//
#include <hip/hip_runtime.h>
#include <hip/hip_bf16.h>

#define NS 8192
#define NQ 8192
#define NTOT 16384
#define KDIM 1024
#define ED 512
#define NC 64
#define PBLK 64   // proto partial blocks along support dim

typedef __attribute__((ext_vector_type(4))) float fx4;
typedef __attribute__((ext_vector_type(4))) int ix4;
typedef __attribute__((ext_vector_type(8))) short sx8;
typedef __attribute__((ext_vector_type(4))) unsigned short ux4;
typedef __attribute__((ext_vector_type(8))) unsigned short ux8;

__device__ __forceinline__ unsigned short f2bf(float f) {
  union { float f; unsigned u; } v; v.f = f;
  unsigned r = v.u + 0x7fffu + ((v.u >> 16) & 1u);   // RNE
  return (unsigned short)(r >> 16);
}
__device__ __forceinline__ float bf2f(unsigned short h) {
  union { unsigned u; float f; } v; v.u = ((unsigned)h) << 16;
  return v.f;
}

// ---------------------------------------------------------------------------
// K0: W [1024,512] fp32 -> Wt [512,1024] bf16 (B^T layout). Block (0,0) also
// zero-inits rowssq (saves a memset node in the graph).
// ---------------------------------------------------------------------------
__global__ __launch_bounds__(256) void k_prep(const float* __restrict__ W,
                                              unsigned short* __restrict__ Wt,
                                              float* __restrict__ rowssq) {
  __shared__ float tile[32][33];
  int k0 = blockIdx.x * 32;
  int n0 = blockIdx.y * 32;
  int tx = threadIdx.x & 31;
  int ty = threadIdx.x >> 5;
#pragma unroll
  for (int i = ty; i < 32; i += 8)
    tile[i][tx] = W[(size_t)(k0 + i) * ED + n0 + tx];
  __syncthreads();
#pragma unroll
  for (int i = ty; i < 32; i += 8)
    Wt[(size_t)(n0 + i) * KDIM + k0 + tx] = f2bf(tile[tx][i]);
  if (blockIdx.x == 0 && blockIdx.y == 0) {
#pragma unroll
    for (int i = threadIdx.x; i < NTOT; i += 256) rowssq[i] = 0.f;
  }
}

// ---------------------------------------------------------------------------
// K1: emb = X @ W (bf16 out) + per-row sum-of-squares partials into rowssq.
// Tile 128M x 64N, BK=64, grid 1024 (4 blocks/CU resident -> latency hiding).
// Waves 2x2: each wave 64M x 32N = 4x2 mfma accs. LDS [kq][m][8] layouts.
// XCD swizzle: 8 n-blocks sharing an A-slice land on one XCD.
// ---------------------------------------------------------------------------
__global__ __launch_bounds__(256) void k_gemm_embed(
    const float* __restrict__ Xs, const float* __restrict__ Xq,
    const unsigned short* __restrict__ Wt, unsigned short* __restrict__ emb,
    float* __restrict__ rowssq) {
  __shared__ unsigned short Ash[8 * 128 * 8];  // 16 KB [kq][m][8]
  __shared__ unsigned short Bsh[8 * 64 * 8];   //  8 KB [kq][n][8]

  int lid = blockIdx.x;            // 0..1023
  int x = lid & 7;                 // xcd (dispatch round-robin heuristic)
  int g = lid >> 3;                // 0..127
  int m_blk = x * 16 + (g >> 3);   // 0..127
  int n_blk = g & 7;               // 0..7

  const float* X = (m_blk < 64) ? Xs : Xq;
  int row0 = (m_blk & 63) * 128;

  int t = threadIdx.x;
  int lane = t & 63, w = t >> 6;
  int wm = w >> 1, wn = w & 1;
  int quad = lane >> 4, ml = lane & 15;

  fx4 acc[4][2];
#pragma unroll
  for (int i = 0; i < 4; ++i)
#pragma unroll
    for (int j = 0; j < 2; ++j) acc[i][j] = fx4{0.f, 0.f, 0.f, 0.f};

  for (int k0 = 0; k0 < KDIM; k0 += 64) {
    __syncthreads();
    // stage A: 128 m x 64 k, fp32 -> bf16. 1024 chunks of 8 elems, 4/thread.
#pragma unroll
    for (int c = 0; c < 4; ++c) {
      int ch = t + 256 * c;
      int m = ch >> 3, kq = ch & 7;
      const float* src = &X[(size_t)(row0 + m) * KDIM + k0 + kq * 8];
      fx4 v0 = *(const fx4*)src;
      fx4 v1 = *(const fx4*)(src + 4);
      ux8 b;
      b[0] = f2bf(v0.x); b[1] = f2bf(v0.y); b[2] = f2bf(v0.z); b[3] = f2bf(v0.w);
      b[4] = f2bf(v1.x); b[5] = f2bf(v1.y); b[6] = f2bf(v1.z); b[7] = f2bf(v1.w);
      *(ux8*)&Ash[(kq * 128 + m) * 8] = b;
    }
    // stage B: 64 n x 64 k bf16. 512 chunks, 2/thread, 128B coalesced runs.
#pragma unroll
    for (int c = 0; c < 2; ++c) {
      int ch = t + 256 * c;
      int n = ch >> 3, kq = ch & 7;
      *(ix4*)&Bsh[(kq * 64 + n) * 8] =
          *(const ix4*)&Wt[(size_t)(n_blk * 64 + n) * KDIM + k0 + kq * 8];
    }
    __syncthreads();

#pragma unroll
    for (int s = 0; s < 2; ++s) {
      sx8 af[4], bfr[2];
#pragma unroll
      for (int i = 0; i < 4; ++i)
        af[i] = *(const sx8*)&Ash[((s * 4 + quad) * 128 + wm * 64 + i * 16 + ml) * 8];
#pragma unroll
      for (int j = 0; j < 2; ++j)
        bfr[j] = *(const sx8*)&Bsh[((s * 4 + quad) * 64 + wn * 32 + j * 16 + ml) * 8];
#pragma unroll
      for (int i = 0; i < 4; ++i)
#pragma unroll
        for (int j = 0; j < 2; ++j)
          acc[i][j] = __builtin_amdgcn_mfma_f32_16x16x32_bf16(af[i], bfr[j], acc[i][j], 0, 0, 0);
    }
  }

  // epilogue: emb store + row-ssq partial (shfl width-16 + 1 atomic per row)
  int grow = m_blk * 128 + wm * 64;
  int gcol = n_blk * 64 + wn * 32;
#pragma unroll
  for (int i = 0; i < 4; ++i) {
#pragma unroll
    for (int r = 0; r < 4; ++r) {
      int mrow = grow + i * 16 + quad * 4 + r;
#pragma unroll
      for (int j = 0; j < 2; ++j)
        emb[(size_t)mrow * ED + gcol + j * 16 + ml] = f2bf(acc[i][j][r]);
      float p = acc[i][0][r] * acc[i][0][r] + acc[i][1][r] * acc[i][1][r];
#pragma unroll
      for (int off = 1; off < 16; off <<= 1) p += __shfl_xor(p, off, 16);
      if (ml == 0) atomicAdd(&rowssq[mrow], p);
    }
  }
}

// ---------------------------------------------------------------------------
// K2: per-class partial sums of (emb_s / ||s||), LDS-accumulated.
// Grid (PBLK, 2): x = 128-row support chunk, y = dim half (256 dims).
// ---------------------------------------------------------------------------
__global__ __launch_bounds__(256) void k_proto_partial(
    const unsigned short* __restrict__ embS, const float* __restrict__ rowssq,
    const int* __restrict__ labels, float* __restrict__ Ppart) {
  __shared__ float Pl[NC * 256];  // 64 KB
  int t = threadIdx.x;
#pragma unroll
  for (int i = 0; i < NC; ++i) Pl[i * 256 + t] = 0.f;
  __syncthreads();

  int w = t >> 6, lane = t & 63;
  int half = blockIdx.y;
  int row0 = blockIdx.x * (NS / PBLK);
  for (int r = w; r < NS / PBLK; r += 4) {
    int row = row0 + r;
    int lbl = labels[row];
    float scale = 1.0f / fmaxf(sqrtf(rowssq[row]), 1e-12f);
    ux4 e = *(const ux4*)&embS[(size_t)row * ED + half * 256 + lane * 4];
    float* p = &Pl[lbl * 256 + lane * 4];
    atomicAdd(p + 0, bf2f(e.x) * scale);
    atomicAdd(p + 1, bf2f(e.y) * scale);
    atomicAdd(p + 2, bf2f(e.z) * scale);
    atomicAdd(p + 3, bf2f(e.w) * scale);
  }
  __syncthreads();

  float* o = Ppart + (size_t)blockIdx.x * NC * ED + half * 256;
#pragma unroll
  for (int i = 0; i < NC; ++i) o[(size_t)i * ED + t] = Pl[i * 256 + t];
}

// ---------------------------------------------------------------------------
// K3: reduce PBLK partials -> P, emitted as bf16 directly in the MFMA
// B-fragment layout [kq][n][8] consumed by k_scores (no LDS needed there).
// ---------------------------------------------------------------------------
__global__ __launch_bounds__(256) void k_proto_reduce(
    const float* __restrict__ Ppart, unsigned short* __restrict__ Pbf) {
  int idx = blockIdx.x * 256 + threadIdx.x;  // 0..NC*ED-1
  int kq = idx >> 9;           // k-chunk (0..63)
  int n = (idx >> 3) & 63;     // class
  int j = idx & 7;
  int d = kq * 8 + j;          // dim
  float s = 0.f;
#pragma unroll 8
  for (int b = 0; b < PBLK; ++b) s += Ppart[(size_t)b * NC * ED + n * ED + d];
  Pbf[idx] = f2bf(s);
}

// ---------------------------------------------------------------------------
// K4: class_scores = (emb_q @ P^T) / ||q|| + fused softmax.
// One wave per block (16 queries), no LDS/barriers, grid 512 = full coverage.
// B-fragments straight from L2-hot Pbf (64 KB, fragment-layout, coalesced).
// ---------------------------------------------------------------------------
__global__ __launch_bounds__(64) void k_scores(
    const unsigned short* __restrict__ embQ, const float* __restrict__ ssqQ,
    const unsigned short* __restrict__ Pbf, float* __restrict__ out) {
  int lane = threadIdx.x;
  int quad = lane >> 4, ml = lane & 15;
  int qrow0 = blockIdx.x * 16;

  fx4 acc[4];
#pragma unroll
  for (int i = 0; i < 4; ++i) acc[i] = fx4{0.f, 0.f, 0.f, 0.f};

#pragma unroll 4
  for (int ki = 0; ki < 16; ++ki) {
    sx8 a = *(const sx8*)&embQ[(size_t)(qrow0 + ml) * ED + ki * 32 + quad * 8];
#pragma unroll
    for (int nt = 0; nt < 4; ++nt) {
      sx8 b = *(const sx8*)&Pbf[((ki * 4 + quad) * 64 + nt * 16 + ml) * 8];
      acc[nt] = __builtin_amdgcn_mfma_f32_16x16x32_bf16(a, b, acc[nt], 0, 0, 0);
    }
  }

#pragma unroll
  for (int r = 0; r < 4; ++r) {
    int qq = qrow0 + quad * 4 + r;
    float scale = 1.0f / fmaxf(sqrtf(ssqQ[qq]), 1e-12f);
    float s[4];
#pragma unroll
    for (int nt = 0; nt < 4; ++nt) s[nt] = acc[nt][r] * scale;
    float m = fmaxf(fmaxf(s[0], s[1]), fmaxf(s[2], s[3]));
#pragma unroll
    for (int off = 1; off < 16; off <<= 1) m = fmaxf(m, __shfl_xor(m, off, 16));
    float e[4], ssum = 0.f;
#pragma unroll
    for (int nt = 0; nt < 4; ++nt) { e[nt] = __expf(s[nt] - m); ssum += e[nt]; }
#pragma unroll
    for (int off = 1; off < 16; off <<= 1) ssum += __shfl_xor(ssum, off, 16);
    float inv = 1.0f / ssum;
#pragma unroll
    for (int nt = 0; nt < 4; ++nt)
      out[(size_t)qq * NC + nt * 16 + ml] = e[nt] * inv;
  }
}

// ---------------------------------------------------------------------------
extern "C" void kernel_launch(void* const* d_in, const int* in_sizes, int n_in,
                              void* d_out, int out_size, void* d_ws, size_t ws_size,
                              hipStream_t stream) {
  const float* Xs     = (const float*)d_in[0];  // support_data [8192,1024]
  const int*   labels = (const int*)d_in[1];    // support_labels [8192]
  const float* Xq     = (const float*)d_in[2];  // query_data [8192,1024]
  const float* W      = (const float*)d_in[3];  // W [1024,512]
  float* out = (float*)d_out;

  char* ws = (char*)d_ws;
  size_t off = 0;
  unsigned short* Wt  = (unsigned short*)(ws + off); off += (size_t)ED * KDIM * 2;   // 1 MB
  unsigned short* emb = (unsigned short*)(ws + off); off += (size_t)NTOT * ED * 2;   // 16 MB
  float* rowssq = (float*)(ws + off); off += (size_t)NTOT * 4;                       // 64 KB
  float* Ppart  = (float*)(ws + off); off += (size_t)PBLK * NC * ED * 4;             // 8 MB
  unsigned short* Pbf = (unsigned short*)(ws + off); off += (size_t)NC * ED * 2;     // 64 KB

  k_prep<<<dim3(KDIM / 32, ED / 32), 256, 0, stream>>>(W, Wt, rowssq);
  k_gemm_embed<<<1024, 256, 0, stream>>>(Xs, Xq, Wt, emb, rowssq);
  k_proto_partial<<<dim3(PBLK, 2), 256, 0, stream>>>(emb, rowssq, labels, Ppart);
  k_proto_reduce<<<NC * ED / 256, 256, 0, stream>>>(Ppart, Pbf);
  k_scores<<<NQ / 16, 64, 0, stream>>>(emb + (size_t)NS * ED, rowssq + NS, Pbf, out);
}

// Round 4
// 219.194 us; speedup vs baseline: 1.0602x; 1.0602x over previous
//
#include <hip/hip_runtime.h>
#include <hip/hip_bf16.h>

#define NS 8192
#define NQ 8192
#define NTOT 16384
#define KDIM 1024
#define ED 512
#define NC 64
#define PBLK 64   // proto partial blocks along support dim

typedef __attribute__((ext_vector_type(4))) float fx4;
typedef __attribute__((ext_vector_type(4))) int ix4;
typedef __attribute__((ext_vector_type(8))) short sx8;
typedef __attribute__((ext_vector_type(4))) unsigned short ux4;
typedef __attribute__((ext_vector_type(8))) unsigned short ux8;

__device__ __forceinline__ unsigned short f2bf(float f) {
  union { float f; unsigned u; } v; v.f = f;
  unsigned r = v.u + 0x7fffu + ((v.u >> 16) & 1u);   // RNE
  return (unsigned short)(r >> 16);
}
__device__ __forceinline__ float bf2f(unsigned short h) {
  union { unsigned u; float f; } v; v.u = ((unsigned)h) << 16;
  return v.f;
}

// ---------------------------------------------------------------------------
// K0: W [1024,512] fp32 -> Wt [512,1024] bf16 (B^T layout). Block (0,0) also
// zero-inits rowssq.
// ---------------------------------------------------------------------------
__global__ __launch_bounds__(256) void k_prep(const float* __restrict__ W,
                                              unsigned short* __restrict__ Wt,
                                              float* __restrict__ rowssq) {
  __shared__ float tile[32][33];
  int k0 = blockIdx.x * 32;
  int n0 = blockIdx.y * 32;
  int tx = threadIdx.x & 31;
  int ty = threadIdx.x >> 5;
#pragma unroll
  for (int i = ty; i < 32; i += 8)
    tile[i][tx] = W[(size_t)(k0 + i) * ED + n0 + tx];
  __syncthreads();
#pragma unroll
  for (int i = ty; i < 32; i += 8)
    Wt[(size_t)(n0 + i) * KDIM + k0 + tx] = f2bf(tile[tx][i]);
  if (blockIdx.x == 0 && blockIdx.y == 0) {
#pragma unroll
    for (int i = threadIdx.x; i < NTOT; i += 256) rowssq[i] = 0.f;
  }
}

// ---------------------------------------------------------------------------
// K1: emb = X @ W (bf16 out) + per-row ssq partials. Tile 128Mx64N, BK=64,
// grid 1024 (4 blocks/CU). LDS rows XOR-swizzled by k-chunk: row m of chunk
// kq stored at (m ^ kq) -> staging ds_write_b128 is conflict-free (the 8
// lanes sharing m spread over all 8 bank-groups); fragment ds_read_b128 is
// 2-way (free, m136). Round-3's unswizzled layout was 8-way on writes
// (SQ_LDS_BANK_CONFLICT 2.2e7 ~= 36us of the 87us).
// ---------------------------------------------------------------------------
__global__ __launch_bounds__(256) void k_gemm_embed(
    const float* __restrict__ Xs, const float* __restrict__ Xq,
    const unsigned short* __restrict__ Wt, unsigned short* __restrict__ emb,
    float* __restrict__ rowssq) {
  __shared__ unsigned short Ash[8 * 128 * 8];  // 16 KB [kq][m^kq][8]
  __shared__ unsigned short Bsh[8 * 64 * 8];   //  8 KB [kq][n^kq][8]

  int lid = blockIdx.x;            // 0..1023
  int x = lid & 7;                 // xcd (dispatch round-robin heuristic)
  int g = lid >> 3;                // 0..127
  int m_blk = x * 16 + (g >> 3);   // 0..127
  int n_blk = g & 7;               // 0..7

  const float* X = (m_blk < 64) ? Xs : Xq;
  int row0 = (m_blk & 63) * 128;

  int t = threadIdx.x;
  int lane = t & 63, w = t >> 6;
  int wm = w >> 1, wn = w & 1;
  int quad = lane >> 4, ml = lane & 15;

  fx4 acc[4][2];
#pragma unroll
  for (int i = 0; i < 4; ++i)
#pragma unroll
    for (int j = 0; j < 2; ++j) acc[i][j] = fx4{0.f, 0.f, 0.f, 0.f};

  for (int k0 = 0; k0 < KDIM; k0 += 64) {
    __syncthreads();
    // stage A: 128 m x 64 k, fp32 -> bf16, swizzled rows
#pragma unroll
    for (int c = 0; c < 4; ++c) {
      int ch = t + 256 * c;
      int m = ch >> 3, kq = ch & 7;
      const float* src = &X[(size_t)(row0 + m) * KDIM + k0 + kq * 8];
      fx4 v0 = *(const fx4*)src;
      fx4 v1 = *(const fx4*)(src + 4);
      ux8 b;
      b[0] = f2bf(v0.x); b[1] = f2bf(v0.y); b[2] = f2bf(v0.z); b[3] = f2bf(v0.w);
      b[4] = f2bf(v1.x); b[5] = f2bf(v1.y); b[6] = f2bf(v1.z); b[7] = f2bf(v1.w);
      *(ux8*)&Ash[(kq * 128 + (m ^ kq)) * 8] = b;
    }
    // stage B: 64 n x 64 k bf16 copy, swizzled rows
#pragma unroll
    for (int c = 0; c < 2; ++c) {
      int ch = t + 256 * c;
      int n = ch >> 3, kq = ch & 7;
      *(ix4*)&Bsh[(kq * 64 + (n ^ kq)) * 8] =
          *(const ix4*)&Wt[(size_t)(n_blk * 64 + n) * KDIM + k0 + kq * 8];
    }
    __syncthreads();

#pragma unroll
    for (int s = 0; s < 2; ++s) {
      int kq = s * 4 + quad;
      sx8 af[4], bfr[2];
#pragma unroll
      for (int i = 0; i < 4; ++i) {
        int row = wm * 64 + i * 16 + ml;
        af[i] = *(const sx8*)&Ash[(kq * 128 + (row ^ kq)) * 8];
      }
#pragma unroll
      for (int j = 0; j < 2; ++j) {
        int nrow = wn * 32 + j * 16 + ml;
        bfr[j] = *(const sx8*)&Bsh[(kq * 64 + (nrow ^ kq)) * 8];
      }
#pragma unroll
      for (int i = 0; i < 4; ++i)
#pragma unroll
        for (int j = 0; j < 2; ++j)
          acc[i][j] = __builtin_amdgcn_mfma_f32_16x16x32_bf16(af[i], bfr[j], acc[i][j], 0, 0, 0);
    }
  }

  // epilogue: emb store + row-ssq partial (shfl width-16 + 1 atomic per row)
  int grow = m_blk * 128 + wm * 64;
  int gcol = n_blk * 64 + wn * 32;
#pragma unroll
  for (int i = 0; i < 4; ++i) {
#pragma unroll
    for (int r = 0; r < 4; ++r) {
      int mrow = grow + i * 16 + quad * 4 + r;
#pragma unroll
      for (int j = 0; j < 2; ++j)
        emb[(size_t)mrow * ED + gcol + j * 16 + ml] = f2bf(acc[i][j][r]);
      float p = acc[i][0][r] * acc[i][0][r] + acc[i][1][r] * acc[i][1][r];
#pragma unroll
      for (int off = 1; off < 16; off <<= 1) p += __shfl_xor(p, off, 16);
      if (ml == 0) atomicAdd(&rowssq[mrow], p);
    }
  }
}

// ---------------------------------------------------------------------------
// K2: per-class partial sums of (emb_s / ||s||), LDS-accumulated.
// ---------------------------------------------------------------------------
__global__ __launch_bounds__(256) void k_proto_partial(
    const unsigned short* __restrict__ embS, const float* __restrict__ rowssq,
    const int* __restrict__ labels, float* __restrict__ Ppart) {
  __shared__ float Pl[NC * 256];  // 64 KB
  int t = threadIdx.x;
#pragma unroll
  for (int i = 0; i < NC; ++i) Pl[i * 256 + t] = 0.f;
  __syncthreads();

  int w = t >> 6, lane = t & 63;
  int half = blockIdx.y;
  int row0 = blockIdx.x * (NS / PBLK);
  for (int r = w; r < NS / PBLK; r += 4) {
    int row = row0 + r;
    int lbl = labels[row];
    float scale = 1.0f / fmaxf(sqrtf(rowssq[row]), 1e-12f);
    ux4 e = *(const ux4*)&embS[(size_t)row * ED + half * 256 + lane * 4];
    float* p = &Pl[lbl * 256 + lane * 4];
    atomicAdd(p + 0, bf2f(e.x) * scale);
    atomicAdd(p + 1, bf2f(e.y) * scale);
    atomicAdd(p + 2, bf2f(e.z) * scale);
    atomicAdd(p + 3, bf2f(e.w) * scale);
  }
  __syncthreads();

  float* o = Ppart + (size_t)blockIdx.x * NC * ED + half * 256;
#pragma unroll
  for (int i = 0; i < NC; ++i) o[(size_t)i * ED + t] = Pl[i * 256 + t];
}

// ---------------------------------------------------------------------------
// K3: reduce PBLK partials -> Pbf (bf16, MFMA B-fragment layout [kq][n][8]).
// ---------------------------------------------------------------------------
__global__ __launch_bounds__(256) void k_proto_reduce(
    const float* __restrict__ Ppart, unsigned short* __restrict__ Pbf) {
  int idx = blockIdx.x * 256 + threadIdx.x;  // 0..NC*ED-1
  int kq = idx >> 9;
  int n = (idx >> 3) & 63;
  int j = idx & 7;
  int d = kq * 8 + j;
  float s = 0.f;
#pragma unroll 8
  for (int b = 0; b < PBLK; ++b) s += Ppart[(size_t)b * NC * ED + n * ED + d];
  Pbf[idx] = f2bf(s);
}

// ---------------------------------------------------------------------------
// K4: class_scores = (emb_q @ P^T) / ||q|| + fused softmax.
// 256-thread blocks (4 waves -> latency hiding), grid 128. Each wave: 16 q.
// B-fragments straight from L2-hot Pbf (64 KB, fragment layout, coalesced).
// ---------------------------------------------------------------------------
__global__ __launch_bounds__(256) void k_scores(
    const unsigned short* __restrict__ embQ, const float* __restrict__ ssqQ,
    const unsigned short* __restrict__ Pbf, float* __restrict__ out) {
  int t = threadIdx.x;
  int lane = t & 63, w = t >> 6;
  int quad = lane >> 4, ml = lane & 15;
  int qrow0 = blockIdx.x * 64 + w * 16;

  fx4 acc[4];
#pragma unroll
  for (int i = 0; i < 4; ++i) acc[i] = fx4{0.f, 0.f, 0.f, 0.f};

#pragma unroll 4
  for (int ki = 0; ki < 16; ++ki) {
    sx8 a = *(const sx8*)&embQ[(size_t)(qrow0 + ml) * ED + ki * 32 + quad * 8];
#pragma unroll
    for (int nt = 0; nt < 4; ++nt) {
      sx8 b = *(const sx8*)&Pbf[((ki * 4 + quad) * 64 + nt * 16 + ml) * 8];
      acc[nt] = __builtin_amdgcn_mfma_f32_16x16x32_bf16(a, b, acc[nt], 0, 0, 0);
    }
  }

#pragma unroll
  for (int r = 0; r < 4; ++r) {
    int qq = qrow0 + quad * 4 + r;
    float scale = 1.0f / fmaxf(sqrtf(ssqQ[qq]), 1e-12f);
    float s[4];
#pragma unroll
    for (int nt = 0; nt < 4; ++nt) s[nt] = acc[nt][r] * scale;
    float m = fmaxf(fmaxf(s[0], s[1]), fmaxf(s[2], s[3]));
#pragma unroll
    for (int off = 1; off < 16; off <<= 1) m = fmaxf(m, __shfl_xor(m, off, 16));
    float e[4], ssum = 0.f;
#pragma unroll
    for (int nt = 0; nt < 4; ++nt) { e[nt] = __expf(s[nt] - m); ssum += e[nt]; }
#pragma unroll
    for (int off = 1; off < 16; off <<= 1) ssum += __shfl_xor(ssum, off, 16);
    float inv = 1.0f / ssum;
#pragma unroll
    for (int nt = 0; nt < 4; ++nt)
      out[(size_t)qq * NC + nt * 16 + ml] = e[nt] * inv;
  }
}

// ---------------------------------------------------------------------------
extern "C" void kernel_launch(void* const* d_in, const int* in_sizes, int n_in,
                              void* d_out, int out_size, void* d_ws, size_t ws_size,
                              hipStream_t stream) {
  const float* Xs     = (const float*)d_in[0];  // support_data [8192,1024]
  const int*   labels = (const int*)d_in[1];    // support_labels [8192]
  const float* Xq     = (const float*)d_in[2];  // query_data [8192,1024]
  const float* W      = (const float*)d_in[3];  // W [1024,512]
  float* out = (float*)d_out;

  char* ws = (char*)d_ws;
  size_t off = 0;
  unsigned short* Wt  = (unsigned short*)(ws + off); off += (size_t)ED * KDIM * 2;   // 1 MB
  unsigned short* emb = (unsigned short*)(ws + off); off += (size_t)NTOT * ED * 2;   // 16 MB
  float* rowssq = (float*)(ws + off); off += (size_t)NTOT * 4;                       // 64 KB
  float* Ppart  = (float*)(ws + off); off += (size_t)PBLK * NC * ED * 4;             // 8 MB
  unsigned short* Pbf = (unsigned short*)(ws + off); off += (size_t)NC * ED * 2;     // 64 KB

  k_prep<<<dim3(KDIM / 32, ED / 32), 256, 0, stream>>>(W, Wt, rowssq);
  k_gemm_embed<<<1024, 256, 0, stream>>>(Xs, Xq, Wt, emb, rowssq);
  k_proto_partial<<<dim3(PBLK, 2), 256, 0, stream>>>(emb, rowssq, labels, Ppart);
  k_proto_reduce<<<NC * ED / 256, 256, 0, stream>>>(Ppart, Pbf);
  k_scores<<<NQ / 64, 256, 0, stream>>>(emb + (size_t)NS * ED, rowssq + NS, Pbf, out);
}

// Round 5
// 203.725 us; speedup vs baseline: 1.1407x; 1.0759x over previous
//
#include <hip/hip_runtime.h>
#include <hip/hip_bf16.h>

#define NS 8192
#define NQ 8192
#define NTOT 16384
#define KDIM 1024
#define ED 512
#define NC 64
#define PBLK 64   // proto partial blocks along support dim

typedef __attribute__((ext_vector_type(4))) float fx4;
typedef __attribute__((ext_vector_type(4))) int ix4;
typedef __attribute__((ext_vector_type(8))) short sx8;
typedef __attribute__((ext_vector_type(4))) unsigned short ux4;
typedef __attribute__((ext_vector_type(8))) unsigned short ux8;

__device__ __forceinline__ unsigned short f2bf(float f) {
  union { float f; unsigned u; } v; v.f = f;
  unsigned r = v.u + 0x7fffu + ((v.u >> 16) & 1u);   // RNE
  return (unsigned short)(r >> 16);
}
__device__ __forceinline__ float bf2f(unsigned short h) {
  union { unsigned u; float f; } v; v.u = ((unsigned)h) << 16;
  return v.f;
}

// ---------------------------------------------------------------------------
// K0: fused prep. Blocks [0,512): W [1024,512] fp32 -> Wt [512,1024] bf16
// (B^T layout). Blocks [512,2560): X fp32 -> Xbf bf16 (support then query,
// one contiguous [16384,1024]); first 8 convert blocks also zero rowssq.
// Converting X ONCE here (16.8M converts) replaces 134M in-GEMM converts
// (R4's dominant VALU term: VALUBusy 23.5% vs MfmaUtil 9%).
// ---------------------------------------------------------------------------
__global__ __launch_bounds__(256) void k_prep(
    const float* __restrict__ W, const float* __restrict__ Xs,
    const float* __restrict__ Xq, unsigned short* __restrict__ Wt,
    unsigned short* __restrict__ Xbf, float* __restrict__ rowssq) {
  __shared__ float tile[32][33];
  int bid = blockIdx.x;
  int t = threadIdx.x;
  if (bid < 512) {
    int k0 = (bid & 31) * 32;
    int n0 = (bid >> 5) * 32;
    int tx = t & 31, ty = t >> 5;
#pragma unroll
    for (int i = ty; i < 32; i += 8)
      tile[i][tx] = W[(size_t)(k0 + i) * ED + n0 + tx];
    __syncthreads();
#pragma unroll
    for (int i = ty; i < 32; i += 8)
      Wt[(size_t)(n0 + i) * KDIM + k0 + tx] = f2bf(tile[tx][i]);
  } else {
    int cb = bid - 512;                       // 0..2047, 8192 elems each
    const float* X = (cb < 1024) ? Xs : Xq;
    size_t src0 = (size_t)(cb & 1023) * 8192;
    size_t dst0 = (size_t)cb * 8192;
#pragma unroll
    for (int c = 0; c < 4; ++c) {
      size_t e = src0 + (size_t)c * 2048 + (size_t)t * 8;
      fx4 v0 = *(const fx4*)&X[e];
      fx4 v1 = *(const fx4*)&X[e + 4];
      ux8 b;
      b[0] = f2bf(v0.x); b[1] = f2bf(v0.y); b[2] = f2bf(v0.z); b[3] = f2bf(v0.w);
      b[4] = f2bf(v1.x); b[5] = f2bf(v1.y); b[6] = f2bf(v1.z); b[7] = f2bf(v1.w);
      *(ux8*)&Xbf[dst0 + (size_t)c * 2048 + (size_t)t * 8] = b;
    }
    if (cb < 8) {
#pragma unroll
      for (int i = t; i < 2048; i += 256) rowssq[cb * 2048 + i] = 0.f;
    }
  }
}

// ---------------------------------------------------------------------------
// K1: emb = Xbf @ W (bf16 in/out) + per-row ssq partials. Tile 128Mx64N,
// BK=64, grid 1024 (4 blocks/CU). Pure-bf16 b128 staging (no converts).
// XOR swizzle (row m of k-chunk kq at m^kq): staging writes conflict-free,
// fragment reads 2-way (free) — measured 0 conflicts in R4.
// ---------------------------------------------------------------------------
__global__ __launch_bounds__(256) void k_gemm_embed(
    const unsigned short* __restrict__ Xbf, const unsigned short* __restrict__ Wt,
    unsigned short* __restrict__ emb, float* __restrict__ rowssq) {
  __shared__ unsigned short Ash[8 * 128 * 8];  // 16 KB [kq][m^kq][8]
  __shared__ unsigned short Bsh[8 * 64 * 8];   //  8 KB [kq][n^kq][8]

  int lid = blockIdx.x;            // 0..1023
  int x = lid & 7;                 // xcd (dispatch round-robin heuristic)
  int g = lid >> 3;                // 0..127
  int m_blk = x * 16 + (g >> 3);   // 0..127
  int n_blk = g & 7;               // 0..7

  const unsigned short* Xrow = Xbf + (size_t)m_blk * 128 * KDIM;

  int t = threadIdx.x;
  int lane = t & 63, w = t >> 6;
  int wm = w >> 1, wn = w & 1;
  int quad = lane >> 4, ml = lane & 15;

  fx4 acc[4][2];
#pragma unroll
  for (int i = 0; i < 4; ++i)
#pragma unroll
    for (int j = 0; j < 2; ++j) acc[i][j] = fx4{0.f, 0.f, 0.f, 0.f};

  for (int k0 = 0; k0 < KDIM; k0 += 64) {
    __syncthreads();
    // stage A: 128 m x 64 k bf16, 1024 16B-chunks, 4/thread
#pragma unroll
    for (int c = 0; c < 4; ++c) {
      int ch = t + 256 * c;
      int m = ch >> 3, kq = ch & 7;
      *(ix4*)&Ash[(kq * 128 + (m ^ kq)) * 8] =
          *(const ix4*)&Xrow[(size_t)m * KDIM + k0 + kq * 8];
    }
    // stage B: 64 n x 64 k bf16, 512 chunks, 2/thread
#pragma unroll
    for (int c = 0; c < 2; ++c) {
      int ch = t + 256 * c;
      int n = ch >> 3, kq = ch & 7;
      *(ix4*)&Bsh[(kq * 64 + (n ^ kq)) * 8] =
          *(const ix4*)&Wt[(size_t)(n_blk * 64 + n) * KDIM + k0 + kq * 8];
    }
    __syncthreads();

#pragma unroll
    for (int s = 0; s < 2; ++s) {
      int kq = s * 4 + quad;
      sx8 af[4], bfr[2];
#pragma unroll
      for (int i = 0; i < 4; ++i) {
        int row = wm * 64 + i * 16 + ml;
        af[i] = *(const sx8*)&Ash[(kq * 128 + (row ^ kq)) * 8];
      }
#pragma unroll
      for (int j = 0; j < 2; ++j) {
        int nrow = wn * 32 + j * 16 + ml;
        bfr[j] = *(const sx8*)&Bsh[(kq * 64 + (nrow ^ kq)) * 8];
      }
#pragma unroll
      for (int i = 0; i < 4; ++i)
#pragma unroll
        for (int j = 0; j < 2; ++j)
          acc[i][j] = __builtin_amdgcn_mfma_f32_16x16x32_bf16(af[i], bfr[j], acc[i][j], 0, 0, 0);
    }
  }

  // epilogue: emb store + row-ssq partial (shfl width-16 + 1 atomic per row)
  int grow = m_blk * 128 + wm * 64;
  int gcol = n_blk * 64 + wn * 32;
#pragma unroll
  for (int i = 0; i < 4; ++i) {
#pragma unroll
    for (int r = 0; r < 4; ++r) {
      int mrow = grow + i * 16 + quad * 4 + r;
#pragma unroll
      for (int j = 0; j < 2; ++j)
        emb[(size_t)mrow * ED + gcol + j * 16 + ml] = f2bf(acc[i][j][r]);
      float p = acc[i][0][r] * acc[i][0][r] + acc[i][1][r] * acc[i][1][r];
#pragma unroll
      for (int off = 1; off < 16; off <<= 1) p += __shfl_xor(p, off, 16);
      if (ml == 0) atomicAdd(&rowssq[mrow], p);
    }
  }
}

// ---------------------------------------------------------------------------
// K2: per-class partial sums of (emb_s / ||s||), LDS-accumulated.
// ---------------------------------------------------------------------------
__global__ __launch_bounds__(256) void k_proto_partial(
    const unsigned short* __restrict__ embS, const float* __restrict__ rowssq,
    const int* __restrict__ labels, float* __restrict__ Ppart) {
  __shared__ float Pl[NC * 256];  // 64 KB
  int t = threadIdx.x;
#pragma unroll
  for (int i = 0; i < NC; ++i) Pl[i * 256 + t] = 0.f;
  __syncthreads();

  int w = t >> 6, lane = t & 63;
  int half = blockIdx.y;
  int row0 = blockIdx.x * (NS / PBLK);
  for (int r = w; r < NS / PBLK; r += 4) {
    int row = row0 + r;
    int lbl = labels[row];
    float scale = 1.0f / fmaxf(sqrtf(rowssq[row]), 1e-12f);
    ux4 e = *(const ux4*)&embS[(size_t)row * ED + half * 256 + lane * 4];
    float* p = &Pl[lbl * 256 + lane * 4];
    atomicAdd(p + 0, bf2f(e.x) * scale);
    atomicAdd(p + 1, bf2f(e.y) * scale);
    atomicAdd(p + 2, bf2f(e.z) * scale);
    atomicAdd(p + 3, bf2f(e.w) * scale);
  }
  __syncthreads();

  float* o = Ppart + (size_t)blockIdx.x * NC * ED + half * 256;
#pragma unroll
  for (int i = 0; i < NC; ++i) o[(size_t)i * ED + t] = Pl[i * 256 + t];
}

// ---------------------------------------------------------------------------
// K3: reduce PBLK partials -> Pbf (bf16, MFMA B-fragment layout [kq][n][8]).
// ---------------------------------------------------------------------------
__global__ __launch_bounds__(256) void k_proto_reduce(
    const float* __restrict__ Ppart, unsigned short* __restrict__ Pbf) {
  int idx = blockIdx.x * 256 + threadIdx.x;  // 0..NC*ED-1
  int kq = idx >> 9;
  int n = (idx >> 3) & 63;
  int j = idx & 7;
  int d = kq * 8 + j;
  float s = 0.f;
#pragma unroll 8
  for (int b = 0; b < PBLK; ++b) s += Ppart[(size_t)b * NC * ED + n * ED + d];
  Pbf[idx] = f2bf(s);
}

// ---------------------------------------------------------------------------
// K4: class_scores = (emb_q @ P^T) / ||q|| + fused softmax.
// 512 single-wave blocks (2/CU, full CU coverage), 16 queries each.
// B-fragments straight from L2-hot Pbf (64 KB, fragment layout).
// ---------------------------------------------------------------------------
__global__ __launch_bounds__(64) void k_scores(
    const unsigned short* __restrict__ embQ, const float* __restrict__ ssqQ,
    const unsigned short* __restrict__ Pbf, float* __restrict__ out) {
  int lane = threadIdx.x;
  int quad = lane >> 4, ml = lane & 15;
  int qrow0 = blockIdx.x * 16;

  fx4 acc[4];
#pragma unroll
  for (int i = 0; i < 4; ++i) acc[i] = fx4{0.f, 0.f, 0.f, 0.f};

#pragma unroll 4
  for (int ki = 0; ki < 16; ++ki) {
    sx8 a = *(const sx8*)&embQ[(size_t)(qrow0 + ml) * ED + ki * 32 + quad * 8];
#pragma unroll
    for (int nt = 0; nt < 4; ++nt) {
      sx8 b = *(const sx8*)&Pbf[((ki * 4 + quad) * 64 + nt * 16 + ml) * 8];
      acc[nt] = __builtin_amdgcn_mfma_f32_16x16x32_bf16(a, b, acc[nt], 0, 0, 0);
    }
  }

#pragma unroll
  for (int r = 0; r < 4; ++r) {
    int qq = qrow0 + quad * 4 + r;
    float scale = 1.0f / fmaxf(sqrtf(ssqQ[qq]), 1e-12f);
    float s[4];
#pragma unroll
    for (int nt = 0; nt < 4; ++nt) s[nt] = acc[nt][r] * scale;
    float m = fmaxf(fmaxf(s[0], s[1]), fmaxf(s[2], s[3]));
#pragma unroll
    for (int off = 1; off < 16; off <<= 1) m = fmaxf(m, __shfl_xor(m, off, 16));
    float e[4], ssum = 0.f;
#pragma unroll
    for (int nt = 0; nt < 4; ++nt) { e[nt] = __expf(s[nt] - m); ssum += e[nt]; }
#pragma unroll
    for (int off = 1; off < 16; off <<= 1) ssum += __shfl_xor(ssum, off, 16);
    float inv = 1.0f / ssum;
#pragma unroll
    for (int nt = 0; nt < 4; ++nt)
      out[(size_t)qq * NC + nt * 16 + ml] = e[nt] * inv;
  }
}

// ---------------------------------------------------------------------------
extern "C" void kernel_launch(void* const* d_in, const int* in_sizes, int n_in,
                              void* d_out, int out_size, void* d_ws, size_t ws_size,
                              hipStream_t stream) {
  const float* Xs     = (const float*)d_in[0];  // support_data [8192,1024]
  const int*   labels = (const int*)d_in[1];    // support_labels [8192]
  const float* Xq     = (const float*)d_in[2];  // query_data [8192,1024]
  const float* W      = (const float*)d_in[3];  // W [1024,512]
  float* out = (float*)d_out;

  char* ws = (char*)d_ws;
  size_t off = 0;
  unsigned short* Wt  = (unsigned short*)(ws + off); off += (size_t)ED * KDIM * 2;    // 1 MB
  unsigned short* Xbf = (unsigned short*)(ws + off); off += (size_t)NTOT * KDIM * 2;  // 33.5 MB
  unsigned short* emb = (unsigned short*)(ws + off); off += (size_t)NTOT * ED * 2;    // 16 MB
  float* rowssq = (float*)(ws + off); off += (size_t)NTOT * 4;                        // 64 KB
  float* Ppart  = (float*)(ws + off); off += (size_t)PBLK * NC * ED * 4;              // 8 MB
  unsigned short* Pbf = (unsigned short*)(ws + off); off += (size_t)NC * ED * 2;      // 64 KB

  k_prep<<<2560, 256, 0, stream>>>(W, Xs, Xq, Wt, Xbf, rowssq);
  k_gemm_embed<<<1024, 256, 0, stream>>>(Xbf, Wt, emb, rowssq);
  k_proto_partial<<<dim3(PBLK, 2), 256, 0, stream>>>(emb, rowssq, labels, Ppart);
  k_proto_reduce<<<NC * ED / 256, 256, 0, stream>>>(Ppart, Pbf);
  k_scores<<<NQ / 16, 64, 0, stream>>>(emb + (size_t)NS * ED, rowssq + NS, Pbf, out);
}

// Round 6
// 201.398 us; speedup vs baseline: 1.1539x; 1.0116x over previous
//
#include <hip/hip_runtime.h>
#include <hip/hip_bf16.h>

#define NS 8192
#define NQ 8192
#define NTOT 16384
#define KDIM 1024
#define ED 512
#define NC 64
#define PBLK 64   // proto partial blocks along support dim

typedef __attribute__((ext_vector_type(4))) float fx4;
typedef __attribute__((ext_vector_type(4))) int ix4;
typedef __attribute__((ext_vector_type(8))) short sx8;
typedef __attribute__((ext_vector_type(4))) unsigned short ux4;
typedef __attribute__((ext_vector_type(8))) unsigned short ux8;

__device__ __forceinline__ unsigned short f2bf(float f) {
  union { float f; unsigned u; } v; v.f = f;
  unsigned r = v.u + 0x7fffu + ((v.u >> 16) & 1u);   // RNE
  return (unsigned short)(r >> 16);
}
__device__ __forceinline__ float bf2f(unsigned short h) {
  union { unsigned u; float f; } v; v.u = ((unsigned)h) << 16;
  return v.f;
}

// async global->LDS DMA, 16 B per lane. LDS dest = wave-uniform base + lane*16.
__device__ __forceinline__ void async_ld16(const void* g, void* l) {
  __builtin_amdgcn_global_load_lds(
      (const __attribute__((address_space(1))) unsigned int*)g,
      (__attribute__((address_space(3))) unsigned int*)l, 16, 0, 0);
}

// ---------------------------------------------------------------------------
// K0: fused prep. Blocks [0,512): W -> Wt bf16 (B^T). Blocks [512,2560):
// X fp32 -> Xbf bf16; first 8 convert blocks also zero rowssq.
// ---------------------------------------------------------------------------
__global__ __launch_bounds__(256) void k_prep(
    const float* __restrict__ W, const float* __restrict__ Xs,
    const float* __restrict__ Xq, unsigned short* __restrict__ Wt,
    unsigned short* __restrict__ Xbf, float* __restrict__ rowssq) {
  __shared__ float tile[32][33];
  int bid = blockIdx.x;
  int t = threadIdx.x;
  if (bid < 512) {
    int k0 = (bid & 31) * 32;
    int n0 = (bid >> 5) * 32;
    int tx = t & 31, ty = t >> 5;
#pragma unroll
    for (int i = ty; i < 32; i += 8)
      tile[i][tx] = W[(size_t)(k0 + i) * ED + n0 + tx];
    __syncthreads();
#pragma unroll
    for (int i = ty; i < 32; i += 8)
      Wt[(size_t)(n0 + i) * KDIM + k0 + tx] = f2bf(tile[tx][i]);
  } else {
    int cb = bid - 512;                       // 0..2047, 8192 elems each
    const float* X = (cb < 1024) ? Xs : Xq;
    size_t src0 = (size_t)(cb & 1023) * 8192;
    size_t dst0 = (size_t)cb * 8192;
#pragma unroll
    for (int c = 0; c < 4; ++c) {
      size_t e = src0 + (size_t)c * 2048 + (size_t)t * 8;
      fx4 v0 = *(const fx4*)&X[e];
      fx4 v1 = *(const fx4*)&X[e + 4];
      ux8 b;
      b[0] = f2bf(v0.x); b[1] = f2bf(v0.y); b[2] = f2bf(v0.z); b[3] = f2bf(v0.w);
      b[4] = f2bf(v1.x); b[5] = f2bf(v1.y); b[6] = f2bf(v1.z); b[7] = f2bf(v1.w);
      *(ux8*)&Xbf[dst0 + (size_t)c * 2048 + (size_t)t * 8] = b;
    }
    if (cb < 8) {
#pragma unroll
      for (int i = t; i < 2048; i += 256) rowssq[cb * 2048 + i] = 0.f;
    }
  }
}

// ---------------------------------------------------------------------------
// K1: emb = Xbf @ W + per-row ssq partials. Tile 128Mx64N, BK=64, grid 1024.
// global_load_lds(16B) + DOUBLE-BUFFERED LDS: tile kt+1 DMAs into buf^1 while
// tile kt computes; one barrier/iter, its vmcnt(0) drain hits loads that had
// a full compute phase to land (R5 was 2 barriers/iter with no overlap:
// MfmaUtil 12%, VALUBusy 12.7%, HBM 11% = pure latency-bound).
// Swizzle moved to the GLOBAL side (DMA forces lane-linear LDS): LDS slot ch
// holds kq = (ch&7)^((ch>>3)&7); fragment reads are 2-way (free, m136).
// ---------------------------------------------------------------------------
__global__ __launch_bounds__(256) void k_gemm_embed(
    const unsigned short* __restrict__ Xbf, const unsigned short* __restrict__ Wt,
    unsigned short* __restrict__ emb, float* __restrict__ rowssq) {
  __shared__ unsigned short Ash[2][128 * 8 * 8];  // 16 KB per buf, [m*8+slot][8]
  __shared__ unsigned short Bsh[2][64 * 8 * 8];   //  8 KB per buf, [n*8+slot][8]

  int lid = blockIdx.x;            // 0..1023
  int x = lid & 7;                 // xcd (dispatch round-robin heuristic)
  int g = lid >> 3;                // 0..127
  int m_blk = x * 16 + (g >> 3);   // 0..127
  int n_blk = g & 7;               // 0..7

  const unsigned short* Xrow = Xbf + (size_t)m_blk * 128 * KDIM;
  const unsigned short* Wrow = Wt + (size_t)n_blk * 64 * KDIM;

  int t = threadIdx.x;
  int lane = t & 63, w = t >> 6;
  int wm = w >> 1, wn = w & 1;
  int quad = lane >> 4, ml = lane & 15;

  fx4 acc[4][2];
#pragma unroll
  for (int i = 0; i < 4; ++i)
#pragma unroll
    for (int j = 0; j < 2; ++j) acc[i][j] = fx4{0.f, 0.f, 0.f, 0.f};

  // stage tile kt into buffer b (all DMA, no VGPR round-trip)
  auto stage = [&](int kt, int b) {
    int k0 = kt * 64;
#pragma unroll
    for (int c = 0; c < 4; ++c) {            // A: 1024 chunks, 4/thread
      int ch = t + 256 * c;
      int m = ch >> 3;
      int kq = (ch & 7) ^ (m & 7);           // global-side swizzle
      async_ld16(&Xrow[(size_t)m * KDIM + k0 + kq * 8],
                 &Ash[b][(w * 64 + 256 * c) * 8]);
    }
#pragma unroll
    for (int c = 0; c < 2; ++c) {            // B: 512 chunks, 2/thread
      int ch = t + 256 * c;
      int n = ch >> 3;
      int kq = (ch & 7) ^ (n & 7);
      async_ld16(&Wrow[(size_t)n * KDIM + k0 + kq * 8],
                 &Bsh[b][(w * 64 + 256 * c) * 8]);
    }
  };

  stage(0, 0);
  for (int kt = 0; kt < 16; ++kt) {
    int b = kt & 1;
    __syncthreads();                 // drains DMA for buf b; frees buf b^1
    if (kt < 15) stage(kt + 1, b ^ 1);
#pragma unroll
    for (int s = 0; s < 2; ++s) {
      int kq = s * 4 + quad;
      sx8 af[4], bfr[2];
#pragma unroll
      for (int i = 0; i < 4; ++i) {
        int row = wm * 64 + i * 16 + ml;
        af[i] = *(const sx8*)&Ash[b][(row * 8 + (kq ^ (row & 7))) * 8];
      }
#pragma unroll
      for (int j = 0; j < 2; ++j) {
        int nrow = wn * 32 + j * 16 + ml;
        bfr[j] = *(const sx8*)&Bsh[b][(nrow * 8 + (kq ^ (nrow & 7))) * 8];
      }
#pragma unroll
      for (int i = 0; i < 4; ++i)
#pragma unroll
        for (int j = 0; j < 2; ++j)
          acc[i][j] = __builtin_amdgcn_mfma_f32_16x16x32_bf16(af[i], bfr[j], acc[i][j], 0, 0, 0);
    }
  }

  // epilogue: emb store + row-ssq partial (shfl width-16 + 1 atomic per row)
  int grow = m_blk * 128 + wm * 64;
  int gcol = n_blk * 64 + wn * 32;
#pragma unroll
  for (int i = 0; i < 4; ++i) {
#pragma unroll
    for (int r = 0; r < 4; ++r) {
      int mrow = grow + i * 16 + quad * 4 + r;
#pragma unroll
      for (int j = 0; j < 2; ++j)
        emb[(size_t)mrow * ED + gcol + j * 16 + ml] = f2bf(acc[i][j][r]);
      float p = acc[i][0][r] * acc[i][0][r] + acc[i][1][r] * acc[i][1][r];
#pragma unroll
      for (int off = 1; off < 16; off <<= 1) p += __shfl_xor(p, off, 16);
      if (ml == 0) atomicAdd(&rowssq[mrow], p);
    }
  }
}

// ---------------------------------------------------------------------------
// K2: per-class partial sums of (emb_s / ||s||), LDS-accumulated.
// ---------------------------------------------------------------------------
__global__ __launch_bounds__(256) void k_proto_partial(
    const unsigned short* __restrict__ embS, const float* __restrict__ rowssq,
    const int* __restrict__ labels, float* __restrict__ Ppart) {
  __shared__ float Pl[NC * 256];  // 64 KB
  int t = threadIdx.x;
#pragma unroll
  for (int i = 0; i < NC; ++i) Pl[i * 256 + t] = 0.f;
  __syncthreads();

  int w = t >> 6, lane = t & 63;
  int half = blockIdx.y;
  int row0 = blockIdx.x * (NS / PBLK);
  for (int r = w; r < NS / PBLK; r += 4) {
    int row = row0 + r;
    int lbl = labels[row];
    float scale = 1.0f / fmaxf(sqrtf(rowssq[row]), 1e-12f);
    ux4 e = *(const ux4*)&embS[(size_t)row * ED + half * 256 + lane * 4];
    float* p = &Pl[lbl * 256 + lane * 4];
    atomicAdd(p + 0, bf2f(e.x) * scale);
    atomicAdd(p + 1, bf2f(e.y) * scale);
    atomicAdd(p + 2, bf2f(e.z) * scale);
    atomicAdd(p + 3, bf2f(e.w) * scale);
  }
  __syncthreads();

  float* o = Ppart + (size_t)blockIdx.x * NC * ED + half * 256;
#pragma unroll
  for (int i = 0; i < NC; ++i) o[(size_t)i * ED + t] = Pl[i * 256 + t];
}

// ---------------------------------------------------------------------------
// K3: reduce PBLK partials -> Pbf (bf16, MFMA B-fragment layout [kq][n][8]).
// ---------------------------------------------------------------------------
__global__ __launch_bounds__(256) void k_proto_reduce(
    const float* __restrict__ Ppart, unsigned short* __restrict__ Pbf) {
  int idx = blockIdx.x * 256 + threadIdx.x;  // 0..NC*ED-1
  int kq = idx >> 9;
  int n = (idx >> 3) & 63;
  int j = idx & 7;
  int d = kq * 8 + j;
  float s = 0.f;
#pragma unroll 8
  for (int b = 0; b < PBLK; ++b) s += Ppart[(size_t)b * NC * ED + n * ED + d];
  Pbf[idx] = f2bf(s);
}

// ---------------------------------------------------------------------------
// K4: class_scores = (emb_q @ P^T) / ||q|| + fused softmax.
// 512 single-wave blocks, 16 queries each; B-fragments from L2-hot Pbf.
// ---------------------------------------------------------------------------
__global__ __launch_bounds__(64) void k_scores(
    const unsigned short* __restrict__ embQ, const float* __restrict__ ssqQ,
    const unsigned short* __restrict__ Pbf, float* __restrict__ out) {
  int lane = threadIdx.x;
  int quad = lane >> 4, ml = lane & 15;
  int qrow0 = blockIdx.x * 16;

  fx4 acc[4];
#pragma unroll
  for (int i = 0; i < 4; ++i) acc[i] = fx4{0.f, 0.f, 0.f, 0.f};

#pragma unroll 4
  for (int ki = 0; ki < 16; ++ki) {
    sx8 a = *(const sx8*)&embQ[(size_t)(qrow0 + ml) * ED + ki * 32 + quad * 8];
#pragma unroll
    for (int nt = 0; nt < 4; ++nt) {
      sx8 b = *(const sx8*)&Pbf[((ki * 4 + quad) * 64 + nt * 16 + ml) * 8];
      acc[nt] = __builtin_amdgcn_mfma_f32_16x16x32_bf16(a, b, acc[nt], 0, 0, 0);
    }
  }

#pragma unroll
  for (int r = 0; r < 4; ++r) {
    int qq = qrow0 + quad * 4 + r;
    float scale = 1.0f / fmaxf(sqrtf(ssqQ[qq]), 1e-12f);
    float s[4];
#pragma unroll
    for (int nt = 0; nt < 4; ++nt) s[nt] = acc[nt][r] * scale;
    float m = fmaxf(fmaxf(s[0], s[1]), fmaxf(s[2], s[3]));
#pragma unroll
    for (int off = 1; off < 16; off <<= 1) m = fmaxf(m, __shfl_xor(m, off, 16));
    float e[4], ssum = 0.f;
#pragma unroll
    for (int nt = 0; nt < 4; ++nt) { e[nt] = __expf(s[nt] - m); ssum += e[nt]; }
#pragma unroll
    for (int off = 1; off < 16; off <<= 1) ssum += __shfl_xor(ssum, off, 16);
    float inv = 1.0f / ssum;
#pragma unroll
    for (int nt = 0; nt < 4; ++nt)
      out[(size_t)qq * NC + nt * 16 + ml] = e[nt] * inv;
  }
}

// ---------------------------------------------------------------------------
extern "C" void kernel_launch(void* const* d_in, const int* in_sizes, int n_in,
                              void* d_out, int out_size, void* d_ws, size_t ws_size,
                              hipStream_t stream) {
  const float* Xs     = (const float*)d_in[0];  // support_data [8192,1024]
  const int*   labels = (const int*)d_in[1];    // support_labels [8192]
  const float* Xq     = (const float*)d_in[2];  // query_data [8192,1024]
  const float* W      = (const float*)d_in[3];  // W [1024,512]
  float* out = (float*)d_out;

  char* ws = (char*)d_ws;
  size_t off = 0;
  unsigned short* Wt  = (unsigned short*)(ws + off); off += (size_t)ED * KDIM * 2;    // 1 MB
  unsigned short* Xbf = (unsigned short*)(ws + off); off += (size_t)NTOT * KDIM * 2;  // 33.5 MB
  unsigned short* emb = (unsigned short*)(ws + off); off += (size_t)NTOT * ED * 2;    // 16 MB
  float* rowssq = (float*)(ws + off); off += (size_t)NTOT * 4;                        // 64 KB
  float* Ppart  = (float*)(ws + off); off += (size_t)PBLK * NC * ED * 4;              // 8 MB
  unsigned short* Pbf = (unsigned short*)(ws + off); off += (size_t)NC * ED * 2;      // 64 KB

  k_prep<<<2560, 256, 0, stream>>>(W, Xs, Xq, Wt, Xbf, rowssq);
  k_gemm_embed<<<1024, 256, 0, stream>>>(Xbf, Wt, emb, rowssq);
  k_proto_partial<<<dim3(PBLK, 2), 256, 0, stream>>>(emb, rowssq, labels, Ppart);
  k_proto_reduce<<<NC * ED / 256, 256, 0, stream>>>(Ppart, Pbf);
  k_scores<<<NQ / 16, 64, 0, stream>>>(emb + (size_t)NS * ED, rowssq + NS, Pbf, out);
}

// Round 7
// 180.612 us; speedup vs baseline: 1.2867x; 1.1151x over previous
//
#include <hip/hip_runtime.h>
#include <hip/hip_bf16.h>

#define NS 8192
#define NQ 8192
#define NTOT 16384
#define KDIM 1024
#define ED 512
#define NC 64
#define PBLK 64   // proto partial row-chunks along support dim

typedef __attribute__((ext_vector_type(4))) float fx4;
typedef __attribute__((ext_vector_type(4))) int ix4;
typedef __attribute__((ext_vector_type(8))) short sx8;
typedef __attribute__((ext_vector_type(4))) unsigned short ux4;
typedef __attribute__((ext_vector_type(8))) unsigned short ux8;

__device__ __forceinline__ unsigned short f2bf(float f) {
  union { float f; unsigned u; } v; v.f = f;
  unsigned r = v.u + 0x7fffu + ((v.u >> 16) & 1u);   // RNE
  return (unsigned short)(r >> 16);
}
__device__ __forceinline__ float bf2f(unsigned short h) {
  union { unsigned u; float f; } v; v.u = ((unsigned)h) << 16;
  return v.f;
}

// async global->LDS DMA, 16 B per lane. LDS dest = wave-uniform base + lane*16.
__device__ __forceinline__ void async_ld16(const void* g, void* l) {
  __builtin_amdgcn_global_load_lds(
      (const __attribute__((address_space(1))) unsigned int*)g,
      (__attribute__((address_space(3))) unsigned int*)l, 16, 0, 0);
}

// ---------------------------------------------------------------------------
// K0: fused prep. Blocks [0,512): W -> Wt bf16 (B^T). Blocks [512,2560):
// X fp32 -> Xbf bf16; first 8 convert blocks also zero rowssq.
// ---------------------------------------------------------------------------
__global__ __launch_bounds__(256) void k_prep(
    const float* __restrict__ W, const float* __restrict__ Xs,
    const float* __restrict__ Xq, unsigned short* __restrict__ Wt,
    unsigned short* __restrict__ Xbf, float* __restrict__ rowssq) {
  __shared__ float tile[32][33];
  int bid = blockIdx.x;
  int t = threadIdx.x;
  if (bid < 512) {
    int k0 = (bid & 31) * 32;
    int n0 = (bid >> 5) * 32;
    int tx = t & 31, ty = t >> 5;
#pragma unroll
    for (int i = ty; i < 32; i += 8)
      tile[i][tx] = W[(size_t)(k0 + i) * ED + n0 + tx];
    __syncthreads();
#pragma unroll
    for (int i = ty; i < 32; i += 8)
      Wt[(size_t)(n0 + i) * KDIM + k0 + tx] = f2bf(tile[tx][i]);
  } else {
    int cb = bid - 512;                       // 0..2047, 8192 elems each
    const float* X = (cb < 1024) ? Xs : Xq;
    size_t src0 = (size_t)(cb & 1023) * 8192;
    size_t dst0 = (size_t)cb * 8192;
#pragma unroll
    for (int c = 0; c < 4; ++c) {
      size_t e = src0 + (size_t)c * 2048 + (size_t)t * 8;
      fx4 v0 = *(const fx4*)&X[e];
      fx4 v1 = *(const fx4*)&X[e + 4];
      ux8 b;
      b[0] = f2bf(v0.x); b[1] = f2bf(v0.y); b[2] = f2bf(v0.z); b[3] = f2bf(v0.w);
      b[4] = f2bf(v1.x); b[5] = f2bf(v1.y); b[6] = f2bf(v1.z); b[7] = f2bf(v1.w);
      *(ux8*)&Xbf[dst0 + (size_t)c * 2048 + (size_t)t * 8] = b;
    }
    if (cb < 8) {
#pragma unroll
      for (int i = t; i < 2048; i += 256) rowssq[cb * 2048 + i] = 0.f;
    }
  }
}

// ---------------------------------------------------------------------------
// K1: emb = Xbf @ W + per-row ssq partials. Tile 128Mx64N, BK=64, grid 1024.
// global_load_lds(16B) + double-buffered LDS (one barrier/iter, DMA for tile
// kt+1 lands during tile kt's compute). Global-side XOR swizzle: LDS slot ch
// holds kq = (ch&7)^((ch>>3)&7); fragment reads 2-way (free, m136).
// ---------------------------------------------------------------------------
__global__ __launch_bounds__(256) void k_gemm_embed(
    const unsigned short* __restrict__ Xbf, const unsigned short* __restrict__ Wt,
    unsigned short* __restrict__ emb, float* __restrict__ rowssq) {
  __shared__ unsigned short Ash[2][128 * 8 * 8];  // 16 KB per buf, [m*8+slot][8]
  __shared__ unsigned short Bsh[2][64 * 8 * 8];   //  8 KB per buf, [n*8+slot][8]

  int lid = blockIdx.x;            // 0..1023
  int x = lid & 7;                 // xcd (dispatch round-robin heuristic)
  int g = lid >> 3;                // 0..127
  int m_blk = x * 16 + (g >> 3);   // 0..127
  int n_blk = g & 7;               // 0..7

  const unsigned short* Xrow = Xbf + (size_t)m_blk * 128 * KDIM;
  const unsigned short* Wrow = Wt + (size_t)n_blk * 64 * KDIM;

  int t = threadIdx.x;
  int lane = t & 63, w = t >> 6;
  int wm = w >> 1, wn = w & 1;
  int quad = lane >> 4, ml = lane & 15;

  fx4 acc[4][2];
#pragma unroll
  for (int i = 0; i < 4; ++i)
#pragma unroll
    for (int j = 0; j < 2; ++j) acc[i][j] = fx4{0.f, 0.f, 0.f, 0.f};

  auto stage = [&](int kt, int b) {
    int k0 = kt * 64;
#pragma unroll
    for (int c = 0; c < 4; ++c) {            // A: 1024 chunks, 4/thread
      int ch = t + 256 * c;
      int m = ch >> 3;
      int kq = (ch & 7) ^ (m & 7);           // global-side swizzle
      async_ld16(&Xrow[(size_t)m * KDIM + k0 + kq * 8],
                 &Ash[b][(w * 64 + 256 * c) * 8]);
    }
#pragma unroll
    for (int c = 0; c < 2; ++c) {            // B: 512 chunks, 2/thread
      int ch = t + 256 * c;
      int n = ch >> 3;
      int kq = (ch & 7) ^ (n & 7);
      async_ld16(&Wrow[(size_t)n * KDIM + k0 + kq * 8],
                 &Bsh[b][(w * 64 + 256 * c) * 8]);
    }
  };

  stage(0, 0);
  for (int kt = 0; kt < 16; ++kt) {
    int b = kt & 1;
    __syncthreads();                 // drains DMA for buf b; frees buf b^1
    if (kt < 15) stage(kt + 1, b ^ 1);
#pragma unroll
    for (int s = 0; s < 2; ++s) {
      int kq = s * 4 + quad;
      sx8 af[4], bfr[2];
#pragma unroll
      for (int i = 0; i < 4; ++i) {
        int row = wm * 64 + i * 16 + ml;
        af[i] = *(const sx8*)&Ash[b][(row * 8 + (kq ^ (row & 7))) * 8];
      }
#pragma unroll
      for (int j = 0; j < 2; ++j) {
        int nrow = wn * 32 + j * 16 + ml;
        bfr[j] = *(const sx8*)&Bsh[b][(nrow * 8 + (kq ^ (nrow & 7))) * 8];
      }
#pragma unroll
      for (int i = 0; i < 4; ++i)
#pragma unroll
        for (int j = 0; j < 2; ++j)
          acc[i][j] = __builtin_amdgcn_mfma_f32_16x16x32_bf16(af[i], bfr[j], acc[i][j], 0, 0, 0);
    }
  }

  // epilogue: emb store + row-ssq partial (shfl width-16 + 1 atomic per row)
  int grow = m_blk * 128 + wm * 64;
  int gcol = n_blk * 64 + wn * 32;
#pragma unroll
  for (int i = 0; i < 4; ++i) {
#pragma unroll
    for (int r = 0; r < 4; ++r) {
      int mrow = grow + i * 16 + quad * 4 + r;
#pragma unroll
      for (int j = 0; j < 2; ++j)
        emb[(size_t)mrow * ED + gcol + j * 16 + ml] = f2bf(acc[i][j][r]);
      float p = acc[i][0][r] * acc[i][0][r] + acc[i][1][r] * acc[i][1][r];
#pragma unroll
      for (int off = 1; off < 16; off <<= 1) p += __shfl_xor(p, off, 16);
      if (ml == 0) atomicAdd(&rowssq[mrow], p);
    }
  }
}

// ---------------------------------------------------------------------------
// K2: per-class partial sums of (emb_s / ||s||), LDS-accumulated.
// R6 version: 128 blocks x 64KB LDS = 4.7% occupancy, 47us (latency-starved).
// Now: grid (64 row-chunks, 8 dim-slices) = 512 blocks, 16 KB LDS
// [64 classes][64 dims], ONE lane-exclusive bank-2-way atomic per row
// (was a 4-deep 8-way-aliased burst). 8 waves/CU, independent row iters.
// ---------------------------------------------------------------------------
__global__ __launch_bounds__(256) void k_proto_partial(
    const unsigned short* __restrict__ embS, const float* __restrict__ rowssq,
    const int* __restrict__ labels, float* __restrict__ Ppart) {
  __shared__ float Pl[NC * 64];  // 16 KB: [class][dim-within-slice]
  int t = threadIdx.x;
#pragma unroll
  for (int i = 0; i < 16; ++i) Pl[i * 256 + t] = 0.f;
  __syncthreads();

  int w = t >> 6, lane = t & 63;
  int ds = blockIdx.y;            // dim slice: dims [ds*64, ds*64+64)
  int row0 = blockIdx.x * (NS / PBLK);
#pragma unroll 4
  for (int r = w; r < NS / PBLK; r += 4) {
    int row = row0 + r;
    int lbl = labels[row];
    float scale = 1.0f / fmaxf(sqrtf(rowssq[row]), 1e-12f);
    float v = bf2f(embS[(size_t)row * ED + ds * 64 + lane]) * scale;
    atomicAdd(&Pl[lbl * 64 + lane], v);
  }
  __syncthreads();

  // Ppart layout: [chunk][NC][ED]; this block owns [bx][*][ds*64 +: 64]
  float* o = Ppart + (size_t)blockIdx.x * NC * ED + ds * 64;
#pragma unroll
  for (int i = 0; i < 16; ++i) {
    int idx = i * 256 + t;
    o[(size_t)(idx >> 6) * ED + (idx & 63)] = Pl[idx];
  }
}

// ---------------------------------------------------------------------------
// K3: reduce PBLK partials -> Pbf (bf16, MFMA B-fragment layout [kq][n][8]).
// ---------------------------------------------------------------------------
__global__ __launch_bounds__(256) void k_proto_reduce(
    const float* __restrict__ Ppart, unsigned short* __restrict__ Pbf) {
  int idx = blockIdx.x * 256 + threadIdx.x;  // 0..NC*ED-1
  int kq = idx >> 9;
  int n = (idx >> 3) & 63;
  int j = idx & 7;
  int d = kq * 8 + j;
  float s = 0.f;
#pragma unroll 8
  for (int b = 0; b < PBLK; ++b) s += Ppart[(size_t)b * NC * ED + n * ED + d];
  Pbf[idx] = f2bf(s);
}

// ---------------------------------------------------------------------------
// K4: class_scores = (emb_q @ P^T) / ||q|| + fused softmax.
// 512 single-wave blocks, 16 queries each; B-fragments from L2-hot Pbf.
// ---------------------------------------------------------------------------
__global__ __launch_bounds__(64) void k_scores(
    const unsigned short* __restrict__ embQ, const float* __restrict__ ssqQ,
    const unsigned short* __restrict__ Pbf, float* __restrict__ out) {
  int lane = threadIdx.x;
  int quad = lane >> 4, ml = lane & 15;
  int qrow0 = blockIdx.x * 16;

  fx4 acc[4];
#pragma unroll
  for (int i = 0; i < 4; ++i) acc[i] = fx4{0.f, 0.f, 0.f, 0.f};

#pragma unroll 4
  for (int ki = 0; ki < 16; ++ki) {
    sx8 a = *(const sx8*)&embQ[(size_t)(qrow0 + ml) * ED + ki * 32 + quad * 8];
#pragma unroll
    for (int nt = 0; nt < 4; ++nt) {
      sx8 b = *(const sx8*)&Pbf[((ki * 4 + quad) * 64 + nt * 16 + ml) * 8];
      acc[nt] = __builtin_amdgcn_mfma_f32_16x16x32_bf16(a, b, acc[nt], 0, 0, 0);
    }
  }

#pragma unroll
  for (int r = 0; r < 4; ++r) {
    int qq = qrow0 + quad * 4 + r;
    float scale = 1.0f / fmaxf(sqrtf(ssqQ[qq]), 1e-12f);
    float s[4];
#pragma unroll
    for (int nt = 0; nt < 4; ++nt) s[nt] = acc[nt][r] * scale;
    float m = fmaxf(fmaxf(s[0], s[1]), fmaxf(s[2], s[3]));
#pragma unroll
    for (int off = 1; off < 16; off <<= 1) m = fmaxf(m, __shfl_xor(m, off, 16));
    float e[4], ssum = 0.f;
#pragma unroll
    for (int nt = 0; nt < 4; ++nt) { e[nt] = __expf(s[nt] - m); ssum += e[nt]; }
#pragma unroll
    for (int off = 1; off < 16; off <<= 1) ssum += __shfl_xor(ssum, off, 16);
    float inv = 1.0f / ssum;
#pragma unroll
    for (int nt = 0; nt < 4; ++nt)
      out[(size_t)qq * NC + nt * 16 + ml] = e[nt] * inv;
  }
}

// ---------------------------------------------------------------------------
extern "C" void kernel_launch(void* const* d_in, const int* in_sizes, int n_in,
                              void* d_out, int out_size, void* d_ws, size_t ws_size,
                              hipStream_t stream) {
  const float* Xs     = (const float*)d_in[0];  // support_data [8192,1024]
  const int*   labels = (const int*)d_in[1];    // support_labels [8192]
  const float* Xq     = (const float*)d_in[2];  // query_data [8192,1024]
  const float* W      = (const float*)d_in[3];  // W [1024,512]
  float* out = (float*)d_out;

  char* ws = (char*)d_ws;
  size_t off = 0;
  unsigned short* Wt  = (unsigned short*)(ws + off); off += (size_t)ED * KDIM * 2;    // 1 MB
  unsigned short* Xbf = (unsigned short*)(ws + off); off += (size_t)NTOT * KDIM * 2;  // 33.5 MB
  unsigned short* emb = (unsigned short*)(ws + off); off += (size_t)NTOT * ED * 2;    // 16 MB
  float* rowssq = (float*)(ws + off); off += (size_t)NTOT * 4;                        // 64 KB
  float* Ppart  = (float*)(ws + off); off += (size_t)PBLK * NC * ED * 4;              // 8 MB
  unsigned short* Pbf = (unsigned short*)(ws + off); off += (size_t)NC * ED * 2;      // 64 KB

  k_prep<<<2560, 256, 0, stream>>>(W, Xs, Xq, Wt, Xbf, rowssq);
  k_gemm_embed<<<1024, 256, 0, stream>>>(Xbf, Wt, emb, rowssq);
  k_proto_partial<<<dim3(PBLK, 8), 256, 0, stream>>>(emb, rowssq, labels, Ppart);
  k_proto_reduce<<<NC * ED / 256, 256, 0, stream>>>(Ppart, Pbf);
  k_scores<<<NQ / 16, 64, 0, stream>>>(emb + (size_t)NS * ED, rowssq + NS, Pbf, out);
}

// Round 8
// 169.784 us; speedup vs baseline: 1.3687x; 1.0638x over previous
//
#include <hip/hip_runtime.h>
#include <hip/hip_bf16.h>

#define NS 8192
#define NQ 8192
#define NTOT 16384
#define KDIM 1024
#define ED 512
#define NC 64
#define PBLK 64   // proto partial row-chunks along support dim

typedef __attribute__((ext_vector_type(4))) float fx4;
typedef __attribute__((ext_vector_type(4))) int ix4;
typedef __attribute__((ext_vector_type(8))) short sx8;
typedef __attribute__((ext_vector_type(4))) unsigned short ux4;
typedef __attribute__((ext_vector_type(8))) unsigned short ux8;

__device__ __forceinline__ unsigned short f2bf(float f) {
  union { float f; unsigned u; } v; v.f = f;
  unsigned r = v.u + 0x7fffu + ((v.u >> 16) & 1u);   // RNE
  return (unsigned short)(r >> 16);
}
__device__ __forceinline__ float bf2f(unsigned short h) {
  union { unsigned u; float f; } v; v.u = ((unsigned)h) << 16;
  return v.f;
}

// async global->LDS DMA, 16 B per lane. LDS dest = wave-uniform base + lane*16.
__device__ __forceinline__ void async_ld16(const void* g, void* l) {
  __builtin_amdgcn_global_load_lds(
      (const __attribute__((address_space(1))) unsigned int*)g,
      (__attribute__((address_space(3))) unsigned int*)l, 16, 0, 0);
}

// ---------------------------------------------------------------------------
// K0: fused prep. Blocks [0,512): W -> Wt bf16 (B^T). Blocks [512,2560):
// X fp32 -> Xbf bf16; first 8 convert blocks also zero rowssq.
// ---------------------------------------------------------------------------
__global__ __launch_bounds__(256) void k_prep(
    const float* __restrict__ W, const float* __restrict__ Xs,
    const float* __restrict__ Xq, unsigned short* __restrict__ Wt,
    unsigned short* __restrict__ Xbf, float* __restrict__ rowssq) {
  __shared__ float tile[32][33];
  int bid = blockIdx.x;
  int t = threadIdx.x;
  if (bid < 512) {
    int k0 = (bid & 31) * 32;
    int n0 = (bid >> 5) * 32;
    int tx = t & 31, ty = t >> 5;
#pragma unroll
    for (int i = ty; i < 32; i += 8)
      tile[i][tx] = W[(size_t)(k0 + i) * ED + n0 + tx];
    __syncthreads();
#pragma unroll
    for (int i = ty; i < 32; i += 8)
      Wt[(size_t)(n0 + i) * KDIM + k0 + tx] = f2bf(tile[tx][i]);
  } else {
    int cb = bid - 512;                       // 0..2047, 8192 elems each
    const float* X = (cb < 1024) ? Xs : Xq;
    size_t src0 = (size_t)(cb & 1023) * 8192;
    size_t dst0 = (size_t)cb * 8192;
#pragma unroll
    for (int c = 0; c < 4; ++c) {
      size_t e = src0 + (size_t)c * 2048 + (size_t)t * 8;
      fx4 v0 = *(const fx4*)&X[e];
      fx4 v1 = *(const fx4*)&X[e + 4];
      ux8 b;
      b[0] = f2bf(v0.x); b[1] = f2bf(v0.y); b[2] = f2bf(v0.z); b[3] = f2bf(v0.w);
      b[4] = f2bf(v1.x); b[5] = f2bf(v1.y); b[6] = f2bf(v1.z); b[7] = f2bf(v1.w);
      *(ux8*)&Xbf[dst0 + (size_t)c * 2048 + (size_t)t * 8] = b;
    }
    if (cb < 8) {
#pragma unroll
      for (int i = t; i < 2048; i += 256) rowssq[cb * 2048 + i] = 0.f;
    }
  }
}

// ---------------------------------------------------------------------------
// K1: emb = Xbf @ W + per-row ssq partials. Tile 128Mx128N, BK=64, grid 512
// (2 blocks/CU, LDS 64 KB). Waves 2x2, each 64x64: 16 ds_read_b128 feed
// 32 MFMA per iter (ratio 2 vs R6's 1.33 — R6 was LDS-read-pipe bound:
// read-cycles 15.4us > MFMA 8.3us at ratio 1.33). global_load_lds(16B) +
// double-buffered LDS, one barrier/iter. Global-side XOR swizzle (slot =
// kq^(row&7)): DMA writes lane-linear, fragment reads 2-way (free, m136).
// ---------------------------------------------------------------------------
__global__ __launch_bounds__(256) void k_gemm_embed(
    const unsigned short* __restrict__ Xbf, const unsigned short* __restrict__ Wt,
    unsigned short* __restrict__ emb, float* __restrict__ rowssq) {
  __shared__ unsigned short Ash[2][128 * 8 * 8];  // 16 KB per buf, [m*8+slot][8]
  __shared__ unsigned short Bsh[2][128 * 8 * 8];  // 16 KB per buf, [n*8+slot][8]

  int lid = blockIdx.x;            // 0..511
  int x = lid & 7;                 // xcd (dispatch round-robin heuristic)
  int s = lid >> 3;                // 0..63
  int m_blk = x * 16 + (s >> 2);   // 0..127
  int n_blk = s & 3;               // 0..3

  const unsigned short* Xrow = Xbf + (size_t)m_blk * 128 * KDIM;
  const unsigned short* Wrow = Wt + (size_t)n_blk * 128 * KDIM;

  int t = threadIdx.x;
  int lane = t & 63, w = t >> 6;
  int wm = w >> 1, wn = w & 1;
  int quad = lane >> 4, ml = lane & 15;

  fx4 acc[4][4];
#pragma unroll
  for (int i = 0; i < 4; ++i)
#pragma unroll
    for (int j = 0; j < 4; ++j) acc[i][j] = fx4{0.f, 0.f, 0.f, 0.f};

  auto stage = [&](int kt, int b) {
    int k0 = kt * 64;
#pragma unroll
    for (int c = 0; c < 4; ++c) {            // A: 1024 chunks, 4/thread
      int ch = t + 256 * c;
      int m = ch >> 3;
      int kq = (ch & 7) ^ (m & 7);           // global-side swizzle
      async_ld16(&Xrow[(size_t)m * KDIM + k0 + kq * 8],
                 &Ash[b][(w * 64 + 256 * c) * 8]);
    }
#pragma unroll
    for (int c = 0; c < 4; ++c) {            // B: 1024 chunks, 4/thread
      int ch = t + 256 * c;
      int n = ch >> 3;
      int kq = (ch & 7) ^ (n & 7);
      async_ld16(&Wrow[(size_t)n * KDIM + k0 + kq * 8],
                 &Bsh[b][(w * 64 + 256 * c) * 8]);
    }
  };

  stage(0, 0);
  for (int kt = 0; kt < 16; ++kt) {
    int b = kt & 1;
    __syncthreads();                 // drains DMA for buf b; frees buf b^1
    if (kt < 15) stage(kt + 1, b ^ 1);
#pragma unroll
    for (int s2 = 0; s2 < 2; ++s2) {
      int kq = s2 * 4 + quad;
      sx8 af[4], bfr[4];
#pragma unroll
      for (int i = 0; i < 4; ++i) {
        int row = wm * 64 + i * 16 + ml;
        af[i] = *(const sx8*)&Ash[b][(row * 8 + (kq ^ (row & 7))) * 8];
      }
#pragma unroll
      for (int j = 0; j < 4; ++j) {
        int nrow = wn * 64 + j * 16 + ml;
        bfr[j] = *(const sx8*)&Bsh[b][(nrow * 8 + (kq ^ (nrow & 7))) * 8];
      }
#pragma unroll
      for (int i = 0; i < 4; ++i)
#pragma unroll
        for (int j = 0; j < 4; ++j)
          acc[i][j] = __builtin_amdgcn_mfma_f32_16x16x32_bf16(af[i], bfr[j], acc[i][j], 0, 0, 0);
    }
  }

  // epilogue: emb store + row-ssq partial (shfl width-16 + 1 atomic per row)
  int grow = m_blk * 128 + wm * 64;
  int gcol = n_blk * 128 + wn * 64;
#pragma unroll
  for (int i = 0; i < 4; ++i) {
#pragma unroll
    for (int r = 0; r < 4; ++r) {
      int mrow = grow + i * 16 + quad * 4 + r;
      float p = 0.f;
#pragma unroll
      for (int j = 0; j < 4; ++j) {
        emb[(size_t)mrow * ED + gcol + j * 16 + ml] = f2bf(acc[i][j][r]);
        p += acc[i][j][r] * acc[i][j][r];
      }
#pragma unroll
      for (int off = 1; off < 16; off <<= 1) p += __shfl_xor(p, off, 16);
      if (ml == 0) atomicAdd(&rowssq[mrow], p);
    }
  }
}

// ---------------------------------------------------------------------------
// K2: per-class partial sums of (emb_s / ||s||), LDS-accumulated.
// Grid (64 chunks, 8 dim-slices) = 512 blocks, 16 KB LDS [64c][64d],
// one lane-exclusive atomic per row (2-way banks = free).
// ---------------------------------------------------------------------------
__global__ __launch_bounds__(256) void k_proto_partial(
    const unsigned short* __restrict__ embS, const float* __restrict__ rowssq,
    const int* __restrict__ labels, float* __restrict__ Ppart) {
  __shared__ float Pl[NC * 64];  // 16 KB: [class][dim-within-slice]
  int t = threadIdx.x;
#pragma unroll
  for (int i = 0; i < 16; ++i) Pl[i * 256 + t] = 0.f;
  __syncthreads();

  int w = t >> 6, lane = t & 63;
  int ds = blockIdx.y;            // dim slice: dims [ds*64, ds*64+64)
  int row0 = blockIdx.x * (NS / PBLK);
#pragma unroll 4
  for (int r = w; r < NS / PBLK; r += 4) {
    int row = row0 + r;
    int lbl = labels[row];
    float scale = 1.0f / fmaxf(sqrtf(rowssq[row]), 1e-12f);
    float v = bf2f(embS[(size_t)row * ED + ds * 64 + lane]) * scale;
    atomicAdd(&Pl[lbl * 64 + lane], v);
  }
  __syncthreads();

  float* o = Ppart + (size_t)blockIdx.x * NC * ED + ds * 64;
#pragma unroll
  for (int i = 0; i < 16; ++i) {
    int idx = i * 256 + t;
    o[(size_t)(idx >> 6) * ED + (idx & 63)] = Pl[idx];
  }
}

// ---------------------------------------------------------------------------
// K3: reduce PBLK partials -> Pbf (bf16, MFMA B-fragment layout [kq][n][8]).
// ---------------------------------------------------------------------------
__global__ __launch_bounds__(256) void k_proto_reduce(
    const float* __restrict__ Ppart, unsigned short* __restrict__ Pbf) {
  int idx = blockIdx.x * 256 + threadIdx.x;  // 0..NC*ED-1
  int kq = idx >> 9;
  int n = (idx >> 3) & 63;
  int j = idx & 7;
  int d = kq * 8 + j;
  float s = 0.f;
#pragma unroll 8
  for (int b = 0; b < PBLK; ++b) s += Ppart[(size_t)b * NC * ED + n * ED + d];
  Pbf[idx] = f2bf(s);
}

// ---------------------------------------------------------------------------
// K4: class_scores = (emb_q @ P^T) / ||q|| + fused softmax.
// 512 single-wave blocks, 16 queries each; B-fragments from L2-hot Pbf.
// ---------------------------------------------------------------------------
__global__ __launch_bounds__(64) void k_scores(
    const unsigned short* __restrict__ embQ, const float* __restrict__ ssqQ,
    const unsigned short* __restrict__ Pbf, float* __restrict__ out) {
  int lane = threadIdx.x;
  int quad = lane >> 4, ml = lane & 15;
  int qrow0 = blockIdx.x * 16;

  fx4 acc[4];
#pragma unroll
  for (int i = 0; i < 4; ++i) acc[i] = fx4{0.f, 0.f, 0.f, 0.f};

#pragma unroll 4
  for (int ki = 0; ki < 16; ++ki) {
    sx8 a = *(const sx8*)&embQ[(size_t)(qrow0 + ml) * ED + ki * 32 + quad * 8];
#pragma unroll
    for (int nt = 0; nt < 4; ++nt) {
      sx8 b = *(const sx8*)&Pbf[((ki * 4 + quad) * 64 + nt * 16 + ml) * 8];
      acc[nt] = __builtin_amdgcn_mfma_f32_16x16x32_bf16(a, b, acc[nt], 0, 0, 0);
    }
  }

#pragma unroll
  for (int r = 0; r < 4; ++r) {
    int qq = qrow0 + quad * 4 + r;
    float scale = 1.0f / fmaxf(sqrtf(ssqQ[qq]), 1e-12f);
    float s[4];
#pragma unroll
    for (int nt = 0; nt < 4; ++nt) s[nt] = acc[nt][r] * scale;
    float m = fmaxf(fmaxf(s[0], s[1]), fmaxf(s[2], s[3]));
#pragma unroll
    for (int off = 1; off < 16; off <<= 1) m = fmaxf(m, __shfl_xor(m, off, 16));
    float e[4], ssum = 0.f;
#pragma unroll
    for (int nt = 0; nt < 4; ++nt) { e[nt] = __expf(s[nt] - m); ssum += e[nt]; }
#pragma unroll
    for (int off = 1; off < 16; off <<= 1) ssum += __shfl_xor(ssum, off, 16);
    float inv = 1.0f / ssum;
#pragma unroll
    for (int nt = 0; nt < 4; ++nt)
      out[(size_t)qq * NC + nt * 16 + ml] = e[nt] * inv;
  }
}

// ---------------------------------------------------------------------------
extern "C" void kernel_launch(void* const* d_in, const int* in_sizes, int n_in,
                              void* d_out, int out_size, void* d_ws, size_t ws_size,
                              hipStream_t stream) {
  const float* Xs     = (const float*)d_in[0];  // support_data [8192,1024]
  const int*   labels = (const int*)d_in[1];    // support_labels [8192]
  const float* Xq     = (const float*)d_in[2];  // query_data [8192,1024]
  const float* W      = (const float*)d_in[3];  // W [1024,512]
  float* out = (float*)d_out;

  char* ws = (char*)d_ws;
  size_t off = 0;
  unsigned short* Wt  = (unsigned short*)(ws + off); off += (size_t)ED * KDIM * 2;    // 1 MB
  unsigned short* Xbf = (unsigned short*)(ws + off); off += (size_t)NTOT * KDIM * 2;  // 33.5 MB
  unsigned short* emb = (unsigned short*)(ws + off); off += (size_t)NTOT * ED * 2;    // 16 MB
  float* rowssq = (float*)(ws + off); off += (size_t)NTOT * 4;                        // 64 KB
  float* Ppart  = (float*)(ws + off); off += (size_t)PBLK * NC * ED * 4;              // 8 MB
  unsigned short* Pbf = (unsigned short*)(ws + off); off += (size_t)NC * ED * 2;      // 64 KB

  k_prep<<<2560, 256, 0, stream>>>(W, Xs, Xq, Wt, Xbf, rowssq);
  k_gemm_embed<<<512, 256, 0, stream>>>(Xbf, Wt, emb, rowssq);
  k_proto_partial<<<dim3(PBLK, 8), 256, 0, stream>>>(emb, rowssq, labels, Ppart);
  k_proto_reduce<<<NC * ED / 256, 256, 0, stream>>>(Ppart, Pbf);
  k_scores<<<NQ / 16, 64, 0, stream>>>(emb + (size_t)NS * ED, rowssq + NS, Pbf, out);
}